// Round 16
// baseline (468.261 us; speedup 1.0000x reference)
//
#include <hip/hip_runtime.h>
#include <math.h>

#define EMBED    256
#define HIDDEN   512
#define Nn       2000
#define Ee       2000
#define BM       128     // edges per tile
#define TILES    8       // tiles per persistent block
#define NBLK     250     // 250 * 8 * 128 = 256000 edges
#define NTHREADS 512     // 8 waves, et=4/nt=2 (wave: all 128 edges x 64 n)
#define PHT      8       // 64-k phases per tile
#define NPH      (TILES * PHT)
#define FP       72      // shorts per feat row (64 + 8 pad; measured 0-conflict)

typedef __attribute__((ext_vector_type(8)))  short bf16x8;
typedef __attribute__((ext_vector_type(16))) float f32x16;

static __device__ __forceinline__ short f2bf(float f) {
  unsigned u = __builtin_bit_cast(unsigned, f);
  u += 0x7fffu + ((u >> 16) & 1u);
  return (short)(u >> 16);
}

static __device__ __forceinline__ bf16x8 cvt8(float4 a, float4 b) {
  bf16x8 v;
  v[0]=f2bf(a.x); v[1]=f2bf(a.y); v[2]=f2bf(a.z); v[3]=f2bf(a.w);
  v[4]=f2bf(b.x); v[5]=f2bf(b.y); v[6]=f2bf(b.z); v[7]=f2bf(b.w);
  return v;
}

#define LBAR() do { asm volatile("s_waitcnt lgkmcnt(0)" ::: "memory"); \
                    __builtin_amdgcn_s_barrier(); \
                    asm volatile("" ::: "memory"); } while (0)

// ---- prep: W1 (513x512 f32 [k][n]) -> fragment-major W1F bf16 ----
// W1F[((tn*32 + tk)*64 + lane)*8 + q] = W1[tk*16 + (lane>>5)*8 + q][tn*32 + (lane&31)]
__global__ void w1f_kernel(const float* __restrict__ W1, short* __restrict__ W1F) {
  const int t  = blockIdx.x * 512 + threadIdx.x;   // 32768 fragment-lanes
  const int l  = t & 63;
  const int tk = (t >> 6) & 31;
  const int tn = t >> 11;
  const int n  = tn * 32 + (l & 31);
  const int k0 = tk * 16 + (l >> 5) * 8;
  bf16x8 v;
#pragma unroll
  for (int q = 0; q < 8; ++q)
    v[q] = f2bf(W1[(size_t)(k0 + q) * HIDDEN + n]);
  *(bf16x8*)(W1F + (size_t)t * 8) = v;
}

// ---- main: burst-ordered vmem queue (wa burst -> g burst -> pure MFMA) ----
__global__ __launch_bounds__(NTHREADS, 2)
void edge_kernel(const float* __restrict__ emb, const float* __restrict__ locs,
                 const int* __restrict__ edges, const int* __restrict__ dbias,
                 const float* __restrict__ W1, const float* __restrict__ b1,
                 const float* __restrict__ W2, const float* __restrict__ b2,
                 const short* __restrict__ W1F, float* __restrict__ out)
{
  __shared__ short feat[3][BM][FP];       // 55,296 B (3-buf 64-k chunks)
  __shared__ float b1_s[HIDDEN], w513_s[HIDDEN], w2_s[HIDDEN];  // 6 KB
  __shared__ float part_s[8][BM];         // 4 KB
  __shared__ float dist_s[2][BM];
  __shared__ int   valid_s[2][BM];
  __shared__ int   ibase_s[2][BM], jbase_s[2][BM];   // total ~69.6 KB

  const int tid = threadIdx.x;

  // bijective XCD-chunked swizzle over 250 blocks (xcd 0,1 -> 32; 2..7 -> 31)
  const int orig = blockIdx.x;
  const int xcd  = orig & 7;
  const int idx  = orig >> 3;
  const int sbid = (xcd < 2 ? xcd * 32 : 64 + (xcd - 2) * 31) + idx;
  const int eblk = sbid * (TILES * BM);

  b1_s[tid]   = b1[tid];
  w513_s[tid] = W1[(size_t)512 * HIDDEN + tid];
  w2_s[tid]   = W2[tid];
  const float b2s_base = b2[0] + (float)dbias[0];

  const int lane = tid & 63;
  const int w    = tid >> 6;      // wave 0..7 -> n-slice [w*64, +64)
  const int ln31 = lane & 31;
  const int kg   = lane >> 5;

  // staging map: 4 threads per edge, 16 floats (64 B) each per 64-k phase
  const int e  = tid >> 2;        // edge 0..127
  const int sq = tid & 3;

  auto do_meta = [&](int T) {     // tid < BM only
    const int g  = eblk + T * BM + tid;
    const int b  = g / Ee;
    const int i0 = edges[2 * g];
    const int j0 = edges[2 * g + 1];
    valid_s[T & 1][tid] = (i0 >= 0) && (j0 >= 0);
    const int ib = b * Nn + (i0 < 0 ? 0 : i0);
    const int jb = b * Nn + (j0 < 0 ? 0 : j0);
    ibase_s[T & 1][tid] = ib;
    jbase_s[T & 1][tid] = jb;
    const float dx = locs[2 * (size_t)ib]     - locs[2 * (size_t)jb];
    const float dy = locs[2 * (size_t)ib + 1] - locs[2 * (size_t)jb + 1];
    dist_s[T & 1][tid] = sqrtf(dx * dx + dy * dy);
  };

  // issue gather burst for phase pp (4 float4 per thread, held in regs)
  auto issue_g = [&](int pp, float4* g) {
    const int T    = pp >> 3;
    const int ph   = pp & 7;
    const int side = ph >> 2;
    const int q    = ph & 3;
    const int rb = side ? jbase_s[T & 1][e] : ibase_s[T & 1][e];
    const float* src = emb + (size_t)rb * EMBED + q * 64 + sq * 16;
    g[0] = *(const float4*)(src);
    g[1] = *(const float4*)(src + 4);
    g[2] = *(const float4*)(src + 8);
    g[3] = *(const float4*)(src + 12);
  };
  auto land_g = [&](int pp, const float4* g) {
    const int buf = pp % 3;
    *(bf16x8*)&feat[buf][e][sq * 16]     = cvt8(g[0], g[1]);
    *(bf16x8*)&feat[buf][e][sq * 16 + 8] = cvt8(g[2], g[3]);
  };

  // ---- prologue: meta(0), stage phases 0,1, issue phase 2 ----
  if (tid < BM) do_meta(0);
  LBAR();
  float4 ga[4], gb4[4];
  issue_g(0, ga);
  issue_g(1, gb4);
  land_g(0, ga);
  land_g(1, gb4);
  issue_g(2, ga);                 // stays in flight across phase 0
  LBAR();

  f32x16 acc[4][2];               // [et][nt]
#pragma unroll
  for (int et = 0; et < 4; ++et)
#pragma unroll
    for (int nt = 0; nt < 2; ++nt)
#pragma unroll
      for (int q = 0; q < 16; ++q) acc[et][nt][q] = 0.f;

  const short* wfb = W1F + (size_t)(w * 2 * 32) * 512 + lane * 8;

#pragma unroll 1
  for (int p = 0; p < NPH; ++p) {
    const int T    = p >> 3;
    const int ph   = p & 7;
    const int side = ph >> 2;
    const int q    = ph & 3;
    const int buf  = p % 3;
    const int k16  = side * 16 + q * 4;

    // ---- wa burst: 8 L2 loads, oldest-in-queue after prior retirements ----
    bf16x8 wa[2][4];
#pragma unroll
    for (int nt = 0; nt < 2; ++nt)
#pragma unroll
      for (int ks = 0; ks < 4; ++ks)
        wa[nt][ks] = *(const bf16x8*)(wfb + (size_t)(nt * 32 + k16 + ks) * 512);
    __builtin_amdgcn_sched_barrier(0);

    // ---- land gather of phase p+2 (issued at p-1; only younger bursts wait) -
    if (p < NPH - 2) land_g(p + 2, ga);
    __builtin_amdgcn_sched_barrier(0);

    // ---- issue gather burst for phase p+3 (newest in queue) ----
    if (p + 3 < NPH) issue_g(p + 3, ga);
    __builtin_amdgcn_sched_barrier(0);

    // ---- pure compute: 4 ks, zero vmem issues ----
#pragma unroll
    for (int ks = 0; ks < 4; ++ks) {
      bf16x8 fb0 = *(const bf16x8*)(&feat[buf][ln31][ks * 16 + kg * 8]);
      bf16x8 fb1 = *(const bf16x8*)(&feat[buf][32 + ln31][ks * 16 + kg * 8]);
      bf16x8 fb2 = *(const bf16x8*)(&feat[buf][64 + ln31][ks * 16 + kg * 8]);
      bf16x8 fb3 = *(const bf16x8*)(&feat[buf][96 + ln31][ks * 16 + kg * 8]);
      __builtin_amdgcn_s_setprio(1);
      acc[0][0] = __builtin_amdgcn_mfma_f32_32x32x16_bf16(wa[0][ks], fb0, acc[0][0], 0, 0, 0);
      acc[0][1] = __builtin_amdgcn_mfma_f32_32x32x16_bf16(wa[1][ks], fb0, acc[0][1], 0, 0, 0);
      acc[1][0] = __builtin_amdgcn_mfma_f32_32x32x16_bf16(wa[0][ks], fb1, acc[1][0], 0, 0, 0);
      acc[1][1] = __builtin_amdgcn_mfma_f32_32x32x16_bf16(wa[1][ks], fb1, acc[1][1], 0, 0, 0);
      acc[2][0] = __builtin_amdgcn_mfma_f32_32x32x16_bf16(wa[0][ks], fb2, acc[2][0], 0, 0, 0);
      acc[2][1] = __builtin_amdgcn_mfma_f32_32x32x16_bf16(wa[1][ks], fb2, acc[2][1], 0, 0, 0);
      acc[3][0] = __builtin_amdgcn_mfma_f32_32x32x16_bf16(wa[0][ks], fb3, acc[3][0], 0, 0, 0);
      acc[3][1] = __builtin_amdgcn_mfma_f32_32x32x16_bf16(wa[1][ks], fb3, acc[3][1], 0, 0, 0);
      __builtin_amdgcn_s_setprio(0);
    }

    // meta for tile T+1 early enough for its first issue at phase 8T+5
    if (ph == 2 && T + 1 < TILES && tid < BM) do_meta(T + 1);

    // ---- tile epilogue ----
    if (ph == 7) {
      const int par = T & 1;
      float dv[4], ps[4];
#pragma unroll
      for (int et = 0; et < 4; ++et) {
        dv[et] = dist_s[par][et * 32 + ln31];
        ps[et] = 0.f;
      }
#pragma unroll
      for (int nt = 0; nt < 2; ++nt) {
#pragma unroll
        for (int r = 0; r < 16; ++r) {
          const int n = w * 64 + nt * 32 + (r & 3) + ((r >> 2) << 3) + (kg << 2);
          const float bias = b1_s[n];
          const float wd   = w513_s[n];
          const float w2v  = w2_s[n];
#pragma unroll
          for (int et = 0; et < 4; ++et) {
            float pv = acc[et][nt][r] + bias + dv[et] * wd;
            ps[et] += fmaxf(pv, 0.f) * w2v;
          }
        }
      }
#pragma unroll
      for (int et = 0; et < 4; ++et) ps[et] += __shfl_xor(ps[et], 32, 64);
      if (lane < 32) {
#pragma unroll
        for (int et = 0; et < 4; ++et) part_s[w][et * 32 + ln31] = ps[et];
      }
      LBAR();
      if (tid < BM) {
        float s = 0.f;
#pragma unroll
        for (int wv = 0; wv < 8; ++wv) s += part_s[wv][tid];
        float logit = s + b2s_base;
        if (!valid_s[par][tid]) logit = -__builtin_inff();
        out[eblk + T * BM + tid] = logit;
      }
#pragma unroll
      for (int et = 0; et < 4; ++et)
#pragma unroll
        for (int nt = 0; nt < 2; ++nt)
#pragma unroll
          for (int q2 = 0; q2 < 16; ++q2) acc[et][nt][q2] = 0.f;
    }
    LBAR();
  }
}

extern "C" void kernel_launch(void* const* d_in, const int* in_sizes, int n_in,
                              void* d_out, int out_size, void* d_ws, size_t ws_size,
                              hipStream_t stream) {
  const float* emb   = (const float*)d_in[0];
  const float* locs  = (const float*)d_in[1];
  const int*   edges = (const int*)d_in[2];
  const int*   dbias = (const int*)d_in[3];
  const float* W1    = (const float*)d_in[4];
  const float* b1    = (const float*)d_in[5];
  const float* W2    = (const float*)d_in[6];
  const float* b2    = (const float*)d_in[7];
  float*       out   = (float*)d_out;
  short*       W1F   = (short*)d_ws;   // 512*512*2 = 512 KiB fragment-major

  w1f_kernel<<<dim3(64), dim3(512), 0, stream>>>(W1, W1F);
  edge_kernel<<<dim3(NBLK), dim3(NTHREADS), 0, stream>>>(
      emb, locs, edges, dbias, W1, b1, W2, b2, (const short*)W1F, out);
}

// Round 17
// 180.955 us; speedup vs baseline: 2.5877x; 2.5877x over previous
//
#include <hip/hip_runtime.h>
#include <math.h>

#define EMBED    256
#define HIDDEN   512
#define Nn       2000
#define Ee       2000
#define BMT      64      // edges per tile
#define TILES    16      // tiles per persistent block (1024 edges)
#define NBLK     250     // 250 * 1024 = 256000 edges
#define NTHREADS 512     // 8 waves; wave w: 64 edges x n-slice [w*64, +64)
#define NPH      (TILES * 8)   // 128 phases of 64-k
#define FP       72      // shorts per feat row (64 + 8 pad; measured 0-conflict)

typedef __attribute__((ext_vector_type(8)))  short bf16x8;
typedef __attribute__((ext_vector_type(16))) float f32x16;

static __device__ __forceinline__ short f2bf(float f) {
  unsigned u = __builtin_bit_cast(unsigned, f);
  u += 0x7fffu + ((u >> 16) & 1u);
  return (short)(u >> 16);
}

static __device__ __forceinline__ bf16x8 cvt8(float4 a, float4 b) {
  bf16x8 v;
  v[0]=f2bf(a.x); v[1]=f2bf(a.y); v[2]=f2bf(a.z); v[3]=f2bf(a.w);
  v[4]=f2bf(b.x); v[5]=f2bf(b.y); v[6]=f2bf(b.z); v[7]=f2bf(b.w);
  return v;
}

#define LBAR() do { asm volatile("s_waitcnt lgkmcnt(0)" ::: "memory"); \
                    __builtin_amdgcn_s_barrier(); \
                    asm volatile("" ::: "memory"); } while (0)

// ---- prep: W1 (513x512 f32 [k][n]) -> fragment-major W1F bf16 ----
// W1F[((tn*32 + tk)*64 + lane)*8 + q] = W1[tk*16 + (lane>>5)*8 + q][tn*32 + (lane&31)]
__global__ void w1f_kernel(const float* __restrict__ W1, short* __restrict__ W1F) {
  const int t  = blockIdx.x * 512 + threadIdx.x;   // 32768 fragment-lanes
  const int l  = t & 63;
  const int tk = (t >> 6) & 31;
  const int tn = t >> 11;
  const int n  = tn * 32 + (l & 31);
  const int k0 = tk * 16 + (l >> 5) * 8;
  bf16x8 v;
#pragma unroll
  for (int q = 0; q < 8; ++q)
    v[q] = f2bf(W1[(size_t)(k0 + q) * HIDDEN + n]);
  *(bf16x8*)(W1F + (size_t)t * 8) = v;
}

// MFMA shorthand
#define MF(A, B, C) __builtin_amdgcn_mfma_f32_32x32x16_bf16((A), (B), (C), 0, 0, 0)

// One 64-k phase. GL0/GL1: regs holding gather for phase P+1 (landed here).
// GS0/GS1: regs to receive gather for phase P+2 (issued here).
#define PHASE(P, GL0, GL1, GS0, GS1) do {                                      \
  const int T_  = (P) >> 3;                                                    \
  const int ph_ = (P) & 7;                                                     \
  /* S1: wa burst -- 8 L2 loads, first in this phase's queue segment */        \
  bf16x8 wa[2][4];                                                             \
  _Pragma("unroll")                                                            \
  for (int nt = 0; nt < 2; ++nt)                                               \
    _Pragma("unroll")                                                          \
    for (int ks = 0; ks < 4; ++ks)                                             \
      wa[nt][ks] = *(const bf16x8*)(wfb + (size_t)(nt * 32 + ph_ * 4 + ks) * 512); \
  __builtin_amdgcn_sched_barrier(0);                                           \
  /* S2: issue gather burst for phase P+2 (newest in queue) */                 \
  if ((P) + 2 < NPH) {                                                         \
    const int pp   = (P) + 2;                                                  \
    const int off_ = (pp >> 3) * BMT + ge;                                     \
    const int rb   = ((pp & 4) ? jbase_a[off_] : ibase_a[off_]);               \
    const float* src_ = emb + (size_t)rb * EMBED + (pp & 3) * 64 + gq * 8;     \
    GS0 = *(const float4*)(src_);                                              \
    GS1 = *(const float4*)(src_ + 4);                                          \
  }                                                                            \
  __builtin_amdgcn_sched_barrier(0);                                           \
  /* S3: land gather of phase P+1 (issued 1 phase ago; counted wait) */        \
  if ((P) + 1 < NPH)                                                           \
    *(bf16x8*)&feat[((P) + 1) & 1][ge][gq * 8] = cvt8(GL0, GL1);               \
  __builtin_amdgcn_sched_barrier(0);                                           \
  /* S4: pure compute -- zero vmem issues; wa wait = counted vmcnt */          \
  _Pragma("unroll")                                                            \
  for (int ks = 0; ks < 4; ++ks) {                                             \
    bf16x8 fb0 = *(const bf16x8*)(&feat[(P) & 1][ln31][ks * 16 + kg * 8]);     \
    bf16x8 fb1 = *(const bf16x8*)(&feat[(P) & 1][32 + ln31][ks * 16 + kg * 8]);\
    __builtin_amdgcn_s_setprio(1);                                             \
    acc00 = MF(wa[0][ks], fb0, acc00);                                         \
    acc01 = MF(wa[1][ks], fb0, acc01);                                         \
    acc10 = MF(wa[0][ks], fb1, acc10);                                         \
    acc11 = MF(wa[1][ks], fb1, acc11);                                         \
    __builtin_amdgcn_s_setprio(0);                                             \
  }                                                                            \
  /* tile epilogue */                                                          \
  if (ph_ == 7) {                                                              \
    const int tb_ = T_ * BMT;                                                  \
    float dv0 = dist_a[tb_ + ln31];                                            \
    float dv1 = dist_a[tb_ + 32 + ln31];                                       \
    float ps0 = 0.f, ps1 = 0.f;                                                \
    _Pragma("unroll")                                                          \
    for (int r = 0; r < 16; ++r) {                                             \
      const int n0 = w * 64 + (r & 3) + ((r >> 2) << 3) + (kg << 2);           \
      const float b0_ = b1_s[n0], wd0_ = w513_s[n0], w20_ = w2_s[n0];          \
      const float b1_ = b1_s[n0 + 32], wd1_ = w513_s[n0 + 32], w21_ = w2_s[n0 + 32]; \
      ps0 += fmaxf(acc00[r] + b0_ + dv0 * wd0_, 0.f) * w20_;                   \
      ps0 += fmaxf(acc01[r] + b1_ + dv0 * wd1_, 0.f) * w21_;                   \
      ps1 += fmaxf(acc10[r] + b0_ + dv1 * wd0_, 0.f) * w20_;                   \
      ps1 += fmaxf(acc11[r] + b1_ + dv1 * wd1_, 0.f) * w21_;                   \
    }                                                                          \
    ps0 += __shfl_xor(ps0, 32, 64);                                            \
    ps1 += __shfl_xor(ps1, 32, 64);                                            \
    if (lane < 32) { part_s[w][ln31] = ps0; part_s[w][32 + ln31] = ps1; }      \
    LBAR();                                                                    \
    if (tid < BMT) {                                                           \
      float s_ = 0.f;                                                          \
      _Pragma("unroll")                                                        \
      for (int wv = 0; wv < 8; ++wv) s_ += part_s[wv][tid];                    \
      float logit_ = s_ + b2s_base;                                            \
      if (!valid_a[tb_ + tid]) logit_ = -__builtin_inff();                     \
      out[eblk + tb_ + tid] = logit_;                                          \
    }                                                                          \
    _Pragma("unroll")                                                          \
    for (int q_ = 0; q_ < 16; ++q_) {                                          \
      acc00[q_] = 0.f; acc01[q_] = 0.f; acc10[q_] = 0.f; acc11[q_] = 0.f;      \
    }                                                                          \
  }                                                                            \
  LBAR();                                                                      \
} while (0)

// ---- main: burst-ordered vmem queue, meta fully precomputed ----
__global__ __launch_bounds__(NTHREADS, 1)
void edge_kernel(const float* __restrict__ emb, const float* __restrict__ locs,
                 const int* __restrict__ edges, const int* __restrict__ dbias,
                 const float* __restrict__ W1, const float* __restrict__ b1,
                 const float* __restrict__ W2, const float* __restrict__ b2,
                 const short* __restrict__ W1F, float* __restrict__ out)
{
  __shared__ short feat[2][BMT][FP];      // 18,432 B (dbuf 64-k chunks)
  __shared__ float b1_s[HIDDEN], w513_s[HIDDEN], w2_s[HIDDEN];  // 6 KB
  __shared__ float part_s[8][BMT];        // 2 KB
  __shared__ float dist_a[TILES * BMT];   // 4 KB  (all tiles precomputed)
  __shared__ int   valid_a[TILES * BMT];  // 4 KB
  __shared__ int   ibase_a[TILES * BMT];  // 4 KB
  __shared__ int   jbase_a[TILES * BMT];  // 4 KB   total ~42.5 KB

  const int tid = threadIdx.x;

  // bijective XCD-chunked swizzle over 250 blocks (xcd 0,1 -> 32; 2..7 -> 31)
  const int orig = blockIdx.x;
  const int xcd  = orig & 7;
  const int idx  = orig >> 3;
  const int sbid = (xcd < 2 ? xcd * 32 : 64 + (xcd - 2) * 31) + idx;
  const int eblk = sbid * (TILES * BMT);

  b1_s[tid]   = b1[tid];
  w513_s[tid] = W1[(size_t)512 * HIDDEN + tid];
  w2_s[tid]   = W2[tid];
  const float b2s_base = b2[0] + (float)dbias[0];

  // ---- prologue: ALL meta (one-time scattered loads; never in main loop) ----
#pragma unroll
  for (int r = 0; r < TILES * BMT / NTHREADS; ++r) {
    const int ii = r * NTHREADS + tid;
    const int g  = eblk + ii;
    const int b  = g / Ee;
    const int i0 = edges[2 * g];
    const int j0 = edges[2 * g + 1];
    valid_a[ii] = (i0 >= 0) && (j0 >= 0);
    const int ib = b * Nn + (i0 < 0 ? 0 : i0);
    const int jb = b * Nn + (j0 < 0 ? 0 : j0);
    ibase_a[ii] = ib;
    jbase_a[ii] = jb;
    const float dx = locs[2 * (size_t)ib]     - locs[2 * (size_t)jb];
    const float dy = locs[2 * (size_t)ib + 1] - locs[2 * (size_t)jb + 1];
    dist_a[ii] = sqrtf(dx * dx + dy * dy);
  }
  LBAR();

  const int lane = tid & 63;
  const int w    = tid >> 6;      // wave 0..7 -> n-slice [w*64, +64)
  const int ln31 = lane & 31;
  const int kg   = lane >> 5;
  const int ge   = tid >> 3;      // gather: edge 0..63
  const int gq   = tid & 7;       // gather: 8-float chunk of the 64-k row

  const short* wfb = W1F + (size_t)(w * 2 * 32) * 512 + lane * 8;

  // ---- stage phase 0; issue gather for phase 1 ----
  float4 gA0, gA1, gB0, gB1;
  {
    const float* src = emb + (size_t)ibase_a[ge] * EMBED + gq * 8;
    float4 f0 = *(const float4*)(src);
    float4 f1 = *(const float4*)(src + 4);
    *(bf16x8*)&feat[0][ge][gq * 8] = cvt8(f0, f1);
  }
  {
    const float* src = emb + (size_t)ibase_a[ge] * EMBED + 64 + gq * 8;
    gA0 = *(const float4*)(src);
    gA1 = *(const float4*)(src + 4);
  }
  LBAR();

  f32x16 acc00, acc01, acc10, acc11;    // [et][nt], named (no arrays -> no scratch)
#pragma unroll
  for (int q = 0; q < 16; ++q) { acc00[q] = 0.f; acc01[q] = 0.f; acc10[q] = 0.f; acc11[q] = 0.f; }

#pragma unroll 1
  for (int p2 = 0; p2 < NPH; p2 += 2) {
    PHASE(p2,     gA0, gA1, gB0, gB1);
    PHASE(p2 + 1, gB0, gB1, gA0, gA1);
  }
}

extern "C" void kernel_launch(void* const* d_in, const int* in_sizes, int n_in,
                              void* d_out, int out_size, void* d_ws, size_t ws_size,
                              hipStream_t stream) {
  const float* emb   = (const float*)d_in[0];
  const float* locs  = (const float*)d_in[1];
  const int*   edges = (const int*)d_in[2];
  const int*   dbias = (const int*)d_in[3];
  const float* W1    = (const float*)d_in[4];
  const float* b1    = (const float*)d_in[5];
  const float* W2    = (const float*)d_in[6];
  const float* b2    = (const float*)d_in[7];
  float*       out   = (float*)d_out;
  short*       W1F   = (short*)d_ws;   // 512*512*2 = 512 KiB fragment-major

  w1f_kernel<<<dim3(64), dim3(512), 0, stream>>>(W1, W1F);
  edge_kernel<<<dim3(NBLK), dim3(NTHREADS), 0, stream>>>(
      emb, locs, edges, dbias, W1, b1, W2, b2, (const short*)W1F, out);
}